// Round 1
// baseline (295.913 us; speedup 1.0000x reference)
//
#include <hip/hip_runtime.h>

#define NEG_INF (-3.402823466e+38f)  // -FLT_MAX

// Branchless insert of 16 window-sums into sorted top-12.
// KLO/KHI: which of the 16 elements produce a valid (inserted) window.
template <int KLO, int KHI>
__device__ __forceinline__ void proc16(const float* __restrict__ p,
                                       float h[4], float& w, float L[12]) {
    float xs[16];
    float4 a = *(const float4*)(p + 0);
    float4 b = *(const float4*)(p + 4);
    float4 c = *(const float4*)(p + 8);
    float4 d = *(const float4*)(p + 12);
    xs[0] = a.x;  xs[1] = a.y;  xs[2] = a.z;  xs[3] = a.w;
    xs[4] = b.x;  xs[5] = b.y;  xs[6] = b.z;  xs[7] = b.w;
    xs[8] = c.x;  xs[9] = c.y;  xs[10] = c.z; xs[11] = c.w;
    xs[12] = d.x; xs[13] = d.y; xs[14] = d.z; xs[15] = d.w;
#pragma unroll
    for (int k = 0; k < 16; ++k) {
        float xv = xs[k];
        w += xv - h[k & 3];   // running 4-window sum (= 4*wmean; /4 folded into epilogue)
        h[k & 3] = xv;        // static index after unroll
        if (k >= KLO && k < KHI) {
            float run = w;
#pragma unroll
            for (int j = 0; j < 12; ++j) {
                float hi = fmaxf(L[j], run);
                run = fminf(L[j], run);
                L[j] = hi;
            }
        }
    }
}

// One block = 256 threads = 256 rows = exactly 2 output entries (F=128).
// Segment-streamed: wave-coalesced global->reg->LDS, then thread-per-row compute.
__global__ __launch_bounds__(256) void ssrp_kernel(const float* __restrict__ x,
                                                   float* __restrict__ out) {
    __shared__ float tile[256 * 20];  // stride 20 floats: aligned float4, balanced banks
    __shared__ float wsum[4];

    const int t = threadIdx.x;
    const long long rowBase = (long long)blockIdx.x * 256;
    const int rq = t >> 2;  // 0..63   row-within-load-group
    const int jq = t & 3;   // 0..3    float4 column within 64B segment

    const float4* __restrict__ x4 = (const float4*)x;

    // prefetch segment 0 (cols 0..3 all valid)
    float4 pf0 = x4[(rowBase + rq) * 250 + jq];
    float4 pf1 = x4[(rowBase + rq + 64) * 250 + jq];
    float4 pf2 = x4[(rowBase + rq + 128) * 250 + jq];
    float4 pf3 = x4[(rowBase + rq + 192) * 250 + jq];

    float L[12];
#pragma unroll
    for (int j = 0; j < 12; ++j) L[j] = NEG_INF;
    float h[4] = {0.f, 0.f, 0.f, 0.f};
    float w = 0.f;

    for (int s = 0; s < 63; ++s) {
        // write prefetched segment to LDS (bytes 80*r + 16*jq: 16B aligned)
        *(float4*)(tile + (rq) * 20 + jq * 4) = pf0;
        *(float4*)(tile + (rq + 64) * 20 + jq * 4) = pf1;
        *(float4*)(tile + (rq + 128) * 20 + jq * 4) = pf2;
        *(float4*)(tile + (rq + 192) * 20 + jq * 4) = pf3;

        // issue prefetch for next segment (overlaps this segment's compute)
        if (s + 1 < 63) {
            const int col = (s + 1) * 4 + jq;  // float4 col, valid < 250
            const bool ok = col < 250;         // only segment 62 has tail
            float4 z = make_float4(0.f, 0.f, 0.f, 0.f);
            pf0 = ok ? x4[(rowBase + rq) * 250 + col] : z;
            pf1 = ok ? x4[(rowBase + rq + 64) * 250 + col] : z;
            pf2 = ok ? x4[(rowBase + rq + 128) * 250 + col] : z;
            pf3 = ok ? x4[(rowBase + rq + 192) * 250 + col] : z;
        }
        __syncthreads();

        const float* p = tile + t * 20;
        if (s == 0) {
            proc16<3, 16>(p, h, w, L);        // first window completes at i=3
        } else if (s == 62) {
            proc16<0, 8>(p, h, w, L);         // i=992..999 valid (t<=996); tail is zero-pad
        } else {
            proc16<0, 16>(p, h, w, L);        // fully valid, zero guard ops
        }
        __syncthreads();
    }

    // sum of top-12 window sums for this row
    float s12 = 0.f;
#pragma unroll
    for (int j = 0; j < 12; ++j) s12 += L[j];

    // wave reduce (64 rows of the same output group: 64 | 128)
#pragma unroll
    for (int off = 1; off < 64; off <<= 1) s12 += __shfl_xor(s12, off, 64);

    if ((t & 63) == 0) wsum[t >> 6] = s12;
    __syncthreads();

    // out = sum(rows)/ (W=4 * K=12 * F=128) ; each output written exactly once
    if (t == 0) out[blockIdx.x * 2 + 0] = (wsum[0] + wsum[1]) * (1.0f / 6144.0f);
    if (t == 128) out[blockIdx.x * 2 + 1] = (wsum[2] + wsum[3]) * (1.0f / 6144.0f);
}

extern "C" void kernel_launch(void* const* d_in, const int* in_sizes, int n_in,
                              void* d_out, int out_size, void* d_ws, size_t ws_size,
                              hipStream_t stream) {
    const float* x = (const float*)d_in[0];
    float* out = (float*)d_out;
    const long long total = (long long)in_sizes[0];  // 16*128*128*1000
    const int rows = (int)(total / 1000);            // 262144
    const int blocks = rows / 256;                   // 1024 (= out_size/2)
    hipLaunchKernelGGL(ssrp_kernel, dim3(blocks), dim3(256), 0, stream, x, out);
}